// Round 2
// baseline (21275.975 us; speedup 1.0000x reference)
//
#include <hip/hip_runtime.h>
#include <hip/hip_bf16.h>
#include <cstdint>
#include <cstddef>

// Problem dims
#define B_   64
#define S_   512
#define T_   256
#define E_   512
#define H_   512
#define KQ_  256
#define V_   1000

typedef unsigned short bf16_t;
typedef __attribute__((ext_vector_type(8))) short short8;   // 8 bf16 (4 VGPRs) — MFMA A/B frag
typedef __attribute__((ext_vector_type(4))) float floatx4;  // MFMA C/D frag

// ---------- small helpers ----------
static __device__ __forceinline__ float bflo(unsigned u){ unsigned x = u << 16;        return __builtin_bit_cast(float, x); }
static __device__ __forceinline__ float bfhi(unsigned u){ unsigned x = u & 0xffff0000u; return __builtin_bit_cast(float, x); }
static __device__ __forceinline__ float bf2f(bf16_t h){ unsigned x = ((unsigned)h) << 16; return __builtin_bit_cast(float, x); }
static __device__ __forceinline__ bf16_t f2bf(float f){
    unsigned u = __builtin_bit_cast(unsigned, f);
    unsigned r = u + 0x7fffu + ((u >> 16) & 1u);   // RNE
    return (bf16_t)(r >> 16);
}
static __device__ __forceinline__ float sigm(float x){ return 1.f / (1.f + __expf(-x)); }
static __device__ __forceinline__ float tanh_(float x){
    float ax = fabsf(x); float t = __expf(-2.f * ax);
    float r = (1.f - t) / (1.f + t);
    return copysignf(r, x);
}
static __device__ __forceinline__ short8 ld8(const bf16_t* p){ return *(const short8*)p; }
static __device__ __forceinline__ floatx4 mfma16(short8 a, short8 b, floatx4 c){
    return __builtin_amdgcn_mfma_f32_16x16x32_bf16(a, b, c, 0, 0, 0);
}

// Shared MFMA K-loop: 4 M-tiles (M=64) x 1 N-tile (N=16) per wave.
// A frag: A[m=lane&15][k=quad*8+j]; B frag from W rows (B^T): B[n=lane&15][k].
// D frag: row(m)=quad*4+r, col(n)=lane&15  (m89-verified convention).
static __device__ __forceinline__ void mfma_kloop(const bf16_t* const rA[4], const bf16_t* rB,
                                                  int K, int quad, floatx4 acc[4]){
    for (int ks = 0; ks < K; ks += 32){
        int ko = ks + quad * 8;
        short8 bf = ld8(rB + ko);
        #pragma unroll
        for (int mi = 0; mi < 4; ++mi)
            acc[mi] = mfma16(ld8(rA[mi] + ko), bf, acc[mi]);
    }
}

// ---------- one-time conversion kernel (runs every call; ws is re-poisoned) ----------
// Segments (element index): Wcat1 | Wcat2 | emb(pad 1024 rows) | W1 | WqT | Wkv | enc | bcat1 | bcat2 | bkv
#define CV_E0 2097152UL
#define CV_E1 4194304UL
#define CV_E2 4718592UL
#define CV_E3 5242880UL
#define CV_E4 5373952UL
#define CV_E5 5767168UL
#define CV_E6 22544384UL
#define CV_E7 22546432UL
#define CV_E8 22548480UL
#define CV_E9 22549248UL

__global__ __launch_bounds__(256) void convert_kernel(
    const float* __restrict__ enc,  const float* __restrict__ Wemb,
    const float* __restrict__ Wih1, const float* __restrict__ Whh1,
    const float* __restrict__ Wih2, const float* __restrict__ Whh2,
    const float* __restrict__ Wq,   const float* __restrict__ Wk,
    const float* __restrict__ Wv,   const float* __restrict__ W1,
    const float* __restrict__ bih1, const float* __restrict__ bhh1,
    const float* __restrict__ bih2, const float* __restrict__ bhh2,
    const float* __restrict__ bk,   const float* __restrict__ bv,
    bf16_t* __restrict__ Wc1,  bf16_t* __restrict__ Wc2, bf16_t* __restrict__ emb16,
    bf16_t* __restrict__ W116, bf16_t* __restrict__ WqT16, bf16_t* __restrict__ Wkv16,
    bf16_t* __restrict__ enc16, float* __restrict__ bcat1, float* __restrict__ bcat2,
    float* __restrict__ bkvO)
{
    for (size_t i = (size_t)blockIdx.x * 256 + threadIdx.x; i < CV_E9; i += (size_t)gridDim.x * 256){
        if (i < CV_E0){ size_t r = i >> 10, k = i & 1023;
            float v_ = (k < 512) ? Wih1[r*512 + k] : Whh1[r*512 + (k - 512)];
            Wc1[i] = f2bf(v_);
        } else if (i < CV_E1){ size_t l = i - CV_E0, r = l >> 10, k = l & 1023;
            float v_ = (k < 512) ? Wih2[r*512 + k] : Whh2[r*512 + (k - 512)];
            Wc2[l] = f2bf(v_);
        } else if (i < CV_E2){ size_t l = i - CV_E1, r = l >> 9, k = l & 511;
            emb16[l] = f2bf(r < 1000 ? Wemb[r*512 + k] : 0.f);
        } else if (i < CV_E3){ size_t l = i - CV_E2;
            W116[l] = f2bf(W1[l]);
        } else if (i < CV_E4){ size_t l = i - CV_E3, h = l >> 8, nn = l & 255;
            WqT16[l] = f2bf(Wq[nn*512 + h]);     // WqT[h][d] = Wq[d][h]
        } else if (i < CV_E5){ size_t l = i - CV_E4, r = l >> 9, k = l & 511;
            float v_ = (r < 256) ? Wk[r*512 + k] : Wv[(r - 256)*512 + k];
            Wkv16[l] = f2bf(v_);
        } else if (i < CV_E6){ size_t l = i - CV_E5;
            enc16[l] = f2bf(enc[l]);
        } else if (i < CV_E7){ size_t l = i - CV_E6; bcat1[l] = bih1[l] + bhh1[l]; }
        else if (i < CV_E8){ size_t l = i - CV_E7; bcat2[l] = bih2[l] + bhh2[l]; }
        else { size_t l = i - CV_E8; bkvO[l] = (l < 256) ? bk[l] : bv[l - 256]; }
    }
}

// ---------- k/v projection: [k|v](m,n) = enc(m,:) . Wkv(n,:) + bkv(n);  M=32768, N=768, K=512 ----------
__global__ __launch_bounds__(256) void gemm_kv_kernel(
    const bf16_t* __restrict__ enc16, const bf16_t* __restrict__ Wkv16,
    const float* __restrict__ bkv, bf16_t* __restrict__ kq16, bf16_t* __restrict__ v16)
{
    const int tid = threadIdx.x, lane = tid & 63, wv = tid >> 6, ml = lane & 15, quad = lane >> 4;
    const int mb = blockIdx.x, nb = blockIdx.y;
    const int n = nb*64 + wv*16 + ml;
    const bf16_t* brow = Wkv16 + (size_t)n * 512;
    const bf16_t* rA[4];
    #pragma unroll
    for (int mi = 0; mi < 4; ++mi) rA[mi] = enc16 + (size_t)(mb*64 + mi*16 + ml) * 512;
    floatx4 acc[4];
    #pragma unroll
    for (int mi = 0; mi < 4; ++mi) acc[mi] = (floatx4){0.f, 0.f, 0.f, 0.f};
    mfma_kloop(rA, brow, 512, quad, acc);
    const float bias = bkv[n];
    #pragma unroll
    for (int mi = 0; mi < 4; ++mi)
        #pragma unroll
        for (int r = 0; r < 4; ++r){
            int m = mb*64 + mi*16 + quad*4 + r;
            float val = acc[mi][r] + bias;
            if (n < 256) kq16[(size_t)m*256 + n] = f2bf(val);
            else         v16 [(size_t)m*512 + (n - 256)] = f2bf(val);
        }
}

// ---------- k2 = k @ Wq  (scores become h2.k2 + bq.k): M=32768, N=512, K=256 ----------
__global__ __launch_bounds__(256) void gemm_k2_kernel(
    const bf16_t* __restrict__ kq16, const bf16_t* __restrict__ WqT16, bf16_t* __restrict__ k216)
{
    const int tid = threadIdx.x, lane = tid & 63, wv = tid >> 6, ml = lane & 15, quad = lane >> 4;
    const int mb = blockIdx.x, nb = blockIdx.y;
    const int n = nb*64 + wv*16 + ml;
    const bf16_t* brow = WqT16 + (size_t)n * 256;
    const bf16_t* rA[4];
    #pragma unroll
    for (int mi = 0; mi < 4; ++mi) rA[mi] = kq16 + (size_t)(mb*64 + mi*16 + ml) * 256;
    floatx4 acc[4];
    #pragma unroll
    for (int mi = 0; mi < 4; ++mi) acc[mi] = (floatx4){0.f, 0.f, 0.f, 0.f};
    mfma_kloop(rA, brow, 256, quad, acc);
    #pragma unroll
    for (int mi = 0; mi < 4; ++mi)
        #pragma unroll
        for (int r = 0; r < 4; ++r){
            int m = mb*64 + mi*16 + quad*4 + r;
            k216[(size_t)m*512 + n] = f2bf(acc[mi][r]);
        }
}

// ---------- kb[m] = k[m,:] . bq ----------
__global__ __launch_bounds__(256) void kbias_kernel(
    const bf16_t* __restrict__ kq16, const float* __restrict__ bq, float* __restrict__ kb)
{
    int m = blockIdx.x * 256 + threadIdx.x;  // 32768 total
    const unsigned* row = (const unsigned*)(kq16 + (size_t)m * 256);
    float acc = 0.f;
    #pragma unroll 8
    for (int i = 0; i < 128; ++i){
        unsigned u = row[i];
        acc += bflo(u) * bq[2*i] + bfhi(u) * bq[2*i + 1];
    }
    kb[m] = acc;
}

// ---------- LSTM cell part (blocks 0..31): gates = [x|h] @ Wcat^T + bcat; M=64, N-tile=16j x 4 gates ----------
static __device__ __forceinline__ void lstm_part(
    int tid, const bf16_t* __restrict__ xrows, const bf16_t* __restrict__ emb,
    const int* __restrict__ y, int t, int use_emb,
    const bf16_t* __restrict__ h_in, bf16_t* __restrict__ h_out,
    float* __restrict__ c_st,
    const bf16_t* __restrict__ Wcat, const float* __restrict__ bcat,
    bf16_t* __restrict__ xcat_out)
{
    __shared__ float lds_g[4][64][17];
    const int lane = tid & 63, wv = tid >> 6, ml = lane & 15, quad = lane >> 4;
    const int j0 = blockIdx.x * 16;
    // wave wv handles gate wv: weight rows wv*512 + j0 + (lane&15)
    const bf16_t* brow = Wcat + (size_t)(wv*512 + j0 + ml) * 1024;
    const bf16_t* rx[4]; const bf16_t* rh[4];
    #pragma unroll
    for (int mi = 0; mi < 4; ++mi){
        int b = mi*16 + ml;
        if (use_emb){
            int tok = (t == 0) ? 0 : y[b * T_ + (t - 1)];
            rx[mi] = emb + (size_t)tok * 512;
        } else {
            rx[mi] = xrows + (size_t)b * 512;
        }
        rh[mi] = h_in + (size_t)b * 512;
    }
    floatx4 acc[4];
    #pragma unroll
    for (int mi = 0; mi < 4; ++mi) acc[mi] = (floatx4){0.f, 0.f, 0.f, 0.f};
    // x phase: k in [0,512)
    for (int ks = 0; ks < 512; ks += 32){
        int ko = ks + quad * 8;
        short8 bf = ld8(brow + ko);
        #pragma unroll
        for (int mi = 0; mi < 4; ++mi) acc[mi] = mfma16(ld8(rx[mi] + ko), bf, acc[mi]);
    }
    // h phase: k in [512,1024)
    for (int ks = 0; ks < 512; ks += 32){
        int ko = ks + quad * 8;
        short8 bf = ld8(brow + 512 + ko);
        #pragma unroll
        for (int mi = 0; mi < 4; ++mi) acc[mi] = mfma16(ld8(rh[mi] + ko), bf, acc[mi]);
    }
    #pragma unroll
    for (int mi = 0; mi < 4; ++mi)
        #pragma unroll
        for (int r = 0; r < 4; ++r)
            lds_g[wv][mi*16 + quad*4 + r][ml] = acc[mi][r];
    __syncthreads();
    // cell update: 256 threads x 4 cells
    const int jj = tid & 15, b0 = tid >> 4;
    const int j = j0 + jj;
    const float bi = bcat[j], bff = bcat[512 + j], bg = bcat[1024 + j], bo = bcat[1536 + j];
    #pragma unroll
    for (int c = 0; c < 4; ++c){
        int b = b0 + 16 * c;
        float gi = lds_g[0][b][jj] + bi;
        float gf = lds_g[1][b][jj] + bff;
        float gg = lds_g[2][b][jj] + bg;
        float go = lds_g[3][b][jj] + bo;
        size_t idx = (size_t)b * 512 + j;
        float cn = sigm(gf) * c_st[idx] + sigm(gi) * tanh_(gg);
        float hn = sigm(go) * tanh_(cn);
        c_st[idx] = cn;
        bf16_t hb = f2bf(hn);
        h_out[idx] = hb;
        if (xcat_out) xcat_out[(size_t)b * 1024 + j] = hb;  // layer-2: h2 half of [h2|ctx]
    }
}

// ---------- step kernel A: LSTM1(t) (blocks 0..31)  ||  hid(t-1) = relu(xcat @ W1^T + b1) (blocks 32..39) ----------
__global__ __launch_bounds__(256) void step_a_kernel(
    const bf16_t* __restrict__ emb16, const int* __restrict__ y, int t, int do_lstm, int do_dense,
    const bf16_t* __restrict__ h1_in, bf16_t* __restrict__ h1_out, float* __restrict__ c1,
    const bf16_t* __restrict__ Wc1, const float* __restrict__ bcat1,
    const bf16_t* __restrict__ xcat, const bf16_t* __restrict__ W116,
    const float* __restrict__ b1, bf16_t* __restrict__ hid)
{
    const int tid = threadIdx.x;
    if (blockIdx.x < 32){
        if (!do_lstm) return;
        lstm_part(tid, nullptr, emb16, y, t, 1, h1_in, h1_out, c1, Wc1, bcat1, nullptr);
    } else {
        if (!do_dense) return;
        const int lane = tid & 63, wv = tid >> 6, ml = lane & 15, quad = lane >> 4;
        const int nb = blockIdx.x - 32;             // 0..7 -> N=512
        const int n = nb*64 + wv*16 + ml;
        const bf16_t* brow = W116 + (size_t)n * 1024;
        const bf16_t* rA[4];
        #pragma unroll
        for (int mi = 0; mi < 4; ++mi) rA[mi] = xcat + (size_t)(mi*16 + ml) * 1024;
        floatx4 acc[4];
        #pragma unroll
        for (int mi = 0; mi < 4; ++mi) acc[mi] = (floatx4){0.f, 0.f, 0.f, 0.f};
        mfma_kloop(rA, brow, 1024, quad, acc);
        const float bias = b1[n];
        #pragma unroll
        for (int mi = 0; mi < 4; ++mi)
            #pragma unroll
            for (int r = 0; r < 4; ++r){
                int m = mi*16 + quad*4 + r;
                float v_ = fmaxf(acc[mi][r] + bias, 0.f);
                hid[(size_t)m*512 + n] = f2bf(v_);
            }
    }
}

// ---------- step kernel B: LSTM2(t) (blocks 0..31)  ||  logits(t-1) = hid @ W_emb^T + b_cls (blocks 32..47) ----------
__global__ __launch_bounds__(256) void step_b_kernel(
    const bf16_t* __restrict__ h1x, const bf16_t* __restrict__ h2_in, bf16_t* __restrict__ h2_out,
    float* __restrict__ c2, const bf16_t* __restrict__ Wc2, const float* __restrict__ bcat2,
    bf16_t* __restrict__ xcat, const bf16_t* __restrict__ hid,
    const bf16_t* __restrict__ emb16, const float* __restrict__ bcls,
    float* __restrict__ out_logits, int t, int do_lstm, int do_dense)
{
    const int tid = threadIdx.x;
    if (blockIdx.x < 32){
        if (!do_lstm) return;
        lstm_part(tid, h1x, nullptr, nullptr, t, 0, h2_in, h2_out, c2, Wc2, bcat2, xcat);
    } else {
        if (!do_dense) return;
        const int lane = tid & 63, wv = tid >> 6, ml = lane & 15, quad = lane >> 4;
        const int nb = blockIdx.x - 32;             // 0..15 -> N=1024 (pad of 1000)
        const int n = nb*64 + wv*16 + ml;
        const bf16_t* brow = emb16 + (size_t)n * 512;   // tied classifier weight (padded rows are zero)
        const bf16_t* rA[4];
        #pragma unroll
        for (int mi = 0; mi < 4; ++mi) rA[mi] = hid + (size_t)(mi*16 + ml) * 512;
        floatx4 acc[4];
        #pragma unroll
        for (int mi = 0; mi < 4; ++mi) acc[mi] = (floatx4){0.f, 0.f, 0.f, 0.f};
        mfma_kloop(rA, brow, 512, quad, acc);
        if (n < V_){
            const float bias = bcls[n];
            #pragma unroll
            for (int mi = 0; mi < 4; ++mi)
                #pragma unroll
                for (int r = 0; r < 4; ++r){
                    int m = mi*16 + quad*4 + r;
                    out_logits[((size_t)m * T_ + (t - 1)) * V_ + n] = acc[mi][r] + bias;
                }
        }
    }
}

// ---------- step kernel C: per-batch attention: scores = (h2.k2 + kb)/16 -> softmax -> ctx ----------
__global__ __launch_bounds__(512) void attn_step_kernel(
    const bf16_t* __restrict__ h2, const bf16_t* __restrict__ k216,
    const bf16_t* __restrict__ v16, const float* __restrict__ kb,
    bf16_t* __restrict__ xcat, float* __restrict__ out_attn, int t)
{
    __shared__ __align__(16) float lds_h2[512];
    __shared__ float lds_attn[512];
    __shared__ float red[16];
    __shared__ float lds_p[1024];
    const int b = blockIdx.x, tid = threadIdx.x;

    lds_h2[tid] = bf2f(h2[(size_t)b * 512 + tid]);
    __syncthreads();

    // scores: thread s = tid dots k2[b][s][:] (512) with h2
    const int s = tid;
    const unsigned* krow = (const unsigned*)(k216 + ((size_t)b * 512 + s) * 512);
    float acc = 0.f;
    #pragma unroll 4
    for (int j = 0; j < 256; j += 4){
        uint4 kv = *(const uint4*)(krow + j);
        float4 ha = *(const float4*)&lds_h2[2*j];
        float4 hb = *(const float4*)&lds_h2[2*j + 4];
        acc += bflo(kv.x)*ha.x + bfhi(kv.x)*ha.y
             + bflo(kv.y)*ha.z + bfhi(kv.y)*ha.w
             + bflo(kv.z)*hb.x + bfhi(kv.z)*hb.y
             + bflo(kv.w)*hb.z + bfhi(kv.w)*hb.w;
    }
    float sc = (acc + kb[(size_t)b * 512 + s]) * 0.0625f;  // scale = 1/sqrt(256)

    // softmax over 512 (8 waves)
    float mx = sc;
    #pragma unroll
    for (int o = 32; o > 0; o >>= 1) mx = fmaxf(mx, __shfl_xor(mx, o, 64));
    if ((tid & 63) == 0) red[tid >> 6] = mx;
    __syncthreads();
    float gmax = red[0];
    #pragma unroll
    for (int i = 1; i < 8; ++i) gmax = fmaxf(gmax, red[i]);
    float e = __expf(sc - gmax);
    float sm = e;
    #pragma unroll
    for (int o = 32; o > 0; o >>= 1) sm += __shfl_xor(sm, o, 64);
    if ((tid & 63) == 0) red[8 + (tid >> 6)] = sm;
    __syncthreads();
    float tot = red[8];
    #pragma unroll
    for (int i = 1; i < 8; ++i) tot += red[8 + i];
    float attn = e / tot;
    lds_attn[s] = attn;
    out_attn[((size_t)b * T_ + t) * S_ + s] = attn;
    __syncthreads();

    // ctx[e] = sum_s attn[s] * v[b][s][e]; split s into halves, 2 e per thread
    const int e2 = (tid & 255) * 2, sh = tid >> 8;
    const unsigned* vp = (const unsigned*)(v16 + (size_t)b * 512 * 512) + (size_t)(sh * 256) * 256 + (e2 >> 1);
    float cx = 0.f, cy = 0.f;
    #pragma unroll 4
    for (int si = 0; si < 256; ++si){
        float a = lds_attn[sh * 256 + si];
        unsigned vv = vp[(size_t)si * 256];
        cx += a * bflo(vv);
        cy += a * bfhi(vv);
    }
    lds_p[sh * 512 + e2]     = cx;
    lds_p[sh * 512 + e2 + 1] = cy;
    __syncthreads();
    float ctxv = lds_p[tid] + lds_p[512 + tid];
    xcat[(size_t)b * 1024 + 512 + tid] = f2bf(ctxv);   // ctx half of [h2|ctx]
}

// ---------------------------------------------------------------------------
extern "C" void kernel_launch(void* const* d_in, const int* in_sizes, int n_in,
                              void* d_out, int out_size, void* d_ws, size_t ws_size,
                              hipStream_t stream)
{
    const float* enc  = (const float*)d_in[0];
    const int*   y    = (const int*)  d_in[1];
    const float* Wemb = (const float*)d_in[2];
    const float* Wih1 = (const float*)d_in[3];  const float* bih1 = (const float*)d_in[4];
    const float* Whh1 = (const float*)d_in[5];  const float* bhh1 = (const float*)d_in[6];
    const float* Wih2 = (const float*)d_in[7];  const float* bih2 = (const float*)d_in[8];
    const float* Whh2 = (const float*)d_in[9];  const float* bhh2 = (const float*)d_in[10];
    const float* Wq   = (const float*)d_in[11]; const float* bq   = (const float*)d_in[12];
    const float* Wk   = (const float*)d_in[13]; const float* bk   = (const float*)d_in[14];
    const float* Wv   = (const float*)d_in[15]; const float* bv   = (const float*)d_in[16];
    const float* W1   = (const float*)d_in[17]; const float* b1   = (const float*)d_in[18];
    const float* bcls = (const float*)d_in[19];

    float* outF = (float*)d_out;
    float* out_logits = outF;
    float* out_attn   = outF + (size_t)B_ * T_ * V_;

    // workspace carve (256B aligned). Peak use ~95 MB.
    size_t off = 0;
    char* wsb = (char*)d_ws;
    auto carve = [&](size_t bytes) -> void* {
        void* p = wsb + off;
        off += (bytes + 255) & ~(size_t)255;
        return p;
    };
    // enc16 is dead after gemm_kv_kernel; k216 aliases the same storage
    // (kernels on one stream serialize, so no overlap hazard).
    bf16_t* enc16 = (bf16_t*)carve((size_t)B_*S_*E_*2);     // 33.5 MB (aliased by k216)
    bf16_t* k216  = enc16;
    bf16_t* kq16  = (bf16_t*)carve((size_t)B_*S_*KQ_*2);    // 16.8 MB
    bf16_t* v16   = (bf16_t*)carve((size_t)B_*S_*E_*2);     // 33.5 MB
    bf16_t* Wc1   = (bf16_t*)carve((size_t)2048*1024*2);
    bf16_t* Wc2   = (bf16_t*)carve((size_t)2048*1024*2);
    bf16_t* emb16 = (bf16_t*)carve((size_t)1024*512*2);     // padded to 1024 rows
    bf16_t* W116  = (bf16_t*)carve((size_t)512*1024*2);
    bf16_t* WqT16 = (bf16_t*)carve((size_t)512*256*2);
    bf16_t* Wkv16 = (bf16_t*)carve((size_t)768*512*2);
    float*  bcat1 = (float*) carve(2048*4);
    float*  bcat2 = (float*) carve(2048*4);
    float*  bkv   = (float*) carve(768*4);
    float*  kb    = (float*) carve((size_t)B_*S_*4);        // 128 KB
    bf16_t* h1b   = (bf16_t*)carve((size_t)2*B_*H_*2);      // ping-pong
    bf16_t* h2b   = (bf16_t*)carve((size_t)2*B_*H_*2);
    float*  c1    = (float*) carve((size_t)B_*H_*4);
    float*  c2    = (float*) carve((size_t)B_*H_*4);
    bf16_t* xcat  = (bf16_t*)carve((size_t)B_*1024*2);      // [h2|ctx]
    bf16_t* hid   = (bf16_t*)carve((size_t)B_*H_*2);

    bf16_t* h1p[2] = { h1b, h1b + (size_t)B_*H_ };
    bf16_t* h2p[2] = { h2b, h2b + (size_t)B_*H_ };

    // zero recurrent state (ws is poisoned before every call)
    hipMemsetAsync(h1b, 0, (size_t)2*B_*H_*2, stream);
    hipMemsetAsync(h2b, 0, (size_t)2*B_*H_*2, stream);
    hipMemsetAsync(c1,  0, (size_t)B_*H_*4, stream);
    hipMemsetAsync(c2,  0, (size_t)B_*H_*4, stream);

    // setup: convert weights/enc, project k/v, fold Wq into k2, bq into kb
    convert_kernel<<<8192, 256, 0, stream>>>(enc, Wemb, Wih1, Whh1, Wih2, Whh2, Wq, Wk, Wv, W1,
                                             bih1, bhh1, bih2, bhh2, bk, bv,
                                             Wc1, Wc2, emb16, W116, WqT16, Wkv16, enc16,
                                             bcat1, bcat2, bkv);
    gemm_kv_kernel<<<dim3(512, 12), 256, 0, stream>>>(enc16, Wkv16, bkv, kq16, v16);
    gemm_k2_kernel<<<dim3(512, 8), 256, 0, stream>>>(kq16, WqT16, k216);
    kbias_kernel<<<128, 256, 0, stream>>>(kq16, bq, kb);

    // scan: A(t)=LSTM1(t)||hid(t-1), B(t)=LSTM2(t)||logits(t-1), C(t)=attention(t)
    for (int t = 0; t <= T_; ++t){
        int do_l = (t < T_) ? 1 : 0;
        int do_d = (t > 0) ? 1 : 0;
        const bf16_t* h1_in = h1p[t & 1];       bf16_t* h1_out = h1p[(t + 1) & 1];
        const bf16_t* h2_in = h2p[t & 1];       bf16_t* h2_out = h2p[(t + 1) & 1];
        step_a_kernel<<<40, 256, 0, stream>>>(emb16, y, t, do_l, do_d,
                                              h1_in, h1_out, c1, Wc1, bcat1,
                                              xcat, W116, b1, hid);
        step_b_kernel<<<48, 256, 0, stream>>>(h1_out, h2_in, h2_out, c2, Wc2, bcat2,
                                              xcat, hid, emb16, bcls, out_logits,
                                              t, do_l, do_d);
        if (t < T_)
            attn_step_kernel<<<64, 512, 0, stream>>>(h2_out, k216, v16, kb, xcat, out_attn, t);
    }
}

// Round 3
// 15490.735 us; speedup vs baseline: 1.3735x; 1.3735x over previous
//
#include <hip/hip_runtime.h>
#include <hip/hip_bf16.h>
#include <cstdint>
#include <cstddef>

// Problem dims
#define B_   64
#define S_   512
#define T_   256
#define E_   512
#define H_   512
#define KQ_  256
#define V_   1000

typedef unsigned short bf16_t;
typedef __attribute__((ext_vector_type(8))) short short8;   // 8 bf16 (4 VGPRs) — MFMA A/B frag
typedef __attribute__((ext_vector_type(4))) float floatx4;  // MFMA C/D frag

// ---------- small helpers ----------
static __device__ __forceinline__ float bflo(unsigned u){ unsigned x = u << 16;        return __builtin_bit_cast(float, x); }
static __device__ __forceinline__ float bfhi(unsigned u){ unsigned x = u & 0xffff0000u; return __builtin_bit_cast(float, x); }
static __device__ __forceinline__ float bf2f(bf16_t h){ unsigned x = ((unsigned)h) << 16; return __builtin_bit_cast(float, x); }
static __device__ __forceinline__ bf16_t f2bf(float f){
    unsigned u = __builtin_bit_cast(unsigned, f);
    unsigned r = u + 0x7fffu + ((u >> 16) & 1u);   // RNE
    return (bf16_t)(r >> 16);
}
static __device__ __forceinline__ float sigm(float x){ return 1.f / (1.f + __expf(-x)); }
static __device__ __forceinline__ float tanh_(float x){
    float ax = fabsf(x); float t = __expf(-2.f * ax);
    float r = (1.f - t) / (1.f + t);
    return copysignf(r, x);
}
static __device__ __forceinline__ short8 ld8(const bf16_t* p){ return *(const short8*)p; }
static __device__ __forceinline__ floatx4 mfma16(short8 a, short8 b, floatx4 c){
    return __builtin_amdgcn_mfma_f32_16x16x32_bf16(a, b, c, 0, 0, 0);
}

// Shared MFMA K-loop: 4 M-tiles (M=64) x 1 N-tile (N=16) per wave.
// A frag: A[m=lane&15][k=quad*8+j]; B frag from W rows (B^T): B[n=lane&15][k].
// D frag: row(m)=quad*4+r, col(n)=lane&15  (m89-verified convention).
static __device__ __forceinline__ void mfma_kloop(const bf16_t* const rA[4], const bf16_t* rB,
                                                  int K, int quad, floatx4 acc[4]){
    for (int ks = 0; ks < K; ks += 32){
        int ko = ks + quad * 8;
        short8 bf = ld8(rB + ko);
        #pragma unroll
        for (int mi = 0; mi < 4; ++mi)
            acc[mi] = mfma16(ld8(rA[mi] + ko), bf, acc[mi]);
    }
}

// ---------- one-time conversion kernel ----------
// Segments (element index): Wcat1 | Wcat2 | emb(pad 1024 rows) | W1 | WqT | Wkv | enc | bcat1 | bcat2 | bkv
#define CV_E0 2097152UL
#define CV_E1 4194304UL
#define CV_E2 4718592UL
#define CV_E3 5242880UL
#define CV_E4 5373952UL
#define CV_E5 5767168UL
#define CV_E6 22544384UL
#define CV_E7 22546432UL
#define CV_E8 22548480UL
#define CV_E9 22549248UL

__global__ __launch_bounds__(256) void convert_kernel(
    const float* __restrict__ enc,  const float* __restrict__ Wemb,
    const float* __restrict__ Wih1, const float* __restrict__ Whh1,
    const float* __restrict__ Wih2, const float* __restrict__ Whh2,
    const float* __restrict__ Wq,   const float* __restrict__ Wk,
    const float* __restrict__ Wv,   const float* __restrict__ W1,
    const float* __restrict__ bih1, const float* __restrict__ bhh1,
    const float* __restrict__ bih2, const float* __restrict__ bhh2,
    const float* __restrict__ bk,   const float* __restrict__ bv,
    bf16_t* __restrict__ Wc1,  bf16_t* __restrict__ Wc2, bf16_t* __restrict__ emb16,
    bf16_t* __restrict__ W116, bf16_t* __restrict__ WqT16, bf16_t* __restrict__ Wkv16,
    bf16_t* __restrict__ enc16, float* __restrict__ bcat1, float* __restrict__ bcat2,
    float* __restrict__ bkvO)
{
    for (size_t i = (size_t)blockIdx.x * 256 + threadIdx.x; i < CV_E9; i += (size_t)gridDim.x * 256){
        if (i < CV_E0){ size_t r = i >> 10, k = i & 1023;
            float v_ = (k < 512) ? Wih1[r*512 + k] : Whh1[r*512 + (k - 512)];
            Wc1[i] = f2bf(v_);
        } else if (i < CV_E1){ size_t l = i - CV_E0, r = l >> 10, k = l & 1023;
            float v_ = (k < 512) ? Wih2[r*512 + k] : Whh2[r*512 + (k - 512)];
            Wc2[l] = f2bf(v_);
        } else if (i < CV_E2){ size_t l = i - CV_E1, r = l >> 9, k = l & 511;
            emb16[l] = f2bf(r < 1000 ? Wemb[r*512 + k] : 0.f);
        } else if (i < CV_E3){ size_t l = i - CV_E2;
            W116[l] = f2bf(W1[l]);
        } else if (i < CV_E4){ size_t l = i - CV_E3, h = l >> 8, nn = l & 255;
            WqT16[l] = f2bf(Wq[nn*512 + h]);     // WqT[h][d] = Wq[d][h]
        } else if (i < CV_E5){ size_t l = i - CV_E4, r = l >> 9, k = l & 511;
            float v_ = (r < 256) ? Wk[r*512 + k] : Wv[(r - 256)*512 + k];
            Wkv16[l] = f2bf(v_);
        } else if (i < CV_E6){ size_t l = i - CV_E5;
            enc16[l] = f2bf(enc[l]);
        } else if (i < CV_E7){ size_t l = i - CV_E6; bcat1[l] = bih1[l] + bhh1[l]; }
        else if (i < CV_E8){ size_t l = i - CV_E7; bcat2[l] = bih2[l] + bhh2[l]; }
        else { size_t l = i - CV_E8; bkvO[l] = (l < 256) ? bk[l] : bv[l - 256]; }
    }
}

// ---------- k/v projection: [k|v](m,n) = enc(m,:) . Wkv(n,:) + bkv(n);  M=32768, N=768, K=512 ----------
__global__ __launch_bounds__(256) void gemm_kv_kernel(
    const bf16_t* __restrict__ enc16, const bf16_t* __restrict__ Wkv16,
    const float* __restrict__ bkv, bf16_t* __restrict__ kq16, bf16_t* __restrict__ v16)
{
    const int tid = threadIdx.x, lane = tid & 63, wv = tid >> 6, ml = lane & 15, quad = lane >> 4;
    const int mb = blockIdx.x, nb = blockIdx.y;
    const int n = nb*64 + wv*16 + ml;
    const bf16_t* brow = Wkv16 + (size_t)n * 512;
    const bf16_t* rA[4];
    #pragma unroll
    for (int mi = 0; mi < 4; ++mi) rA[mi] = enc16 + (size_t)(mb*64 + mi*16 + ml) * 512;
    floatx4 acc[4];
    #pragma unroll
    for (int mi = 0; mi < 4; ++mi) acc[mi] = (floatx4){0.f, 0.f, 0.f, 0.f};
    mfma_kloop(rA, brow, 512, quad, acc);
    const float bias = bkv[n];
    #pragma unroll
    for (int mi = 0; mi < 4; ++mi)
        #pragma unroll
        for (int r = 0; r < 4; ++r){
            int m = mb*64 + mi*16 + quad*4 + r;
            float val = acc[mi][r] + bias;
            if (n < 256) kq16[(size_t)m*256 + n] = f2bf(val);
            else         v16 [(size_t)m*512 + (n - 256)] = f2bf(val);
        }
}

// ---------- k2 = k @ Wq: M=32768, N=512, K=256 ----------
__global__ __launch_bounds__(256) void gemm_k2_kernel(
    const bf16_t* __restrict__ kq16, const bf16_t* __restrict__ WqT16, bf16_t* __restrict__ k216)
{
    const int tid = threadIdx.x, lane = tid & 63, wv = tid >> 6, ml = lane & 15, quad = lane >> 4;
    const int mb = blockIdx.x, nb = blockIdx.y;
    const int n = nb*64 + wv*16 + ml;
    const bf16_t* brow = WqT16 + (size_t)n * 256;
    const bf16_t* rA[4];
    #pragma unroll
    for (int mi = 0; mi < 4; ++mi) rA[mi] = kq16 + (size_t)(mb*64 + mi*16 + ml) * 256;
    floatx4 acc[4];
    #pragma unroll
    for (int mi = 0; mi < 4; ++mi) acc[mi] = (floatx4){0.f, 0.f, 0.f, 0.f};
    mfma_kloop(rA, brow, 256, quad, acc);
    #pragma unroll
    for (int mi = 0; mi < 4; ++mi)
        #pragma unroll
        for (int r = 0; r < 4; ++r){
            int m = mb*64 + mi*16 + quad*4 + r;
            k216[(size_t)m*512 + n] = f2bf(acc[mi][r]);
        }
}

// ---------- kb[m] = k[m,:] . bq ----------
__global__ __launch_bounds__(256) void kbias_kernel(
    const bf16_t* __restrict__ kq16, const float* __restrict__ bq, float* __restrict__ kb)
{
    int m = blockIdx.x * 256 + threadIdx.x;  // 32768 total
    const unsigned* row = (const unsigned*)(kq16 + (size_t)m * 256);
    float acc = 0.f;
    #pragma unroll 8
    for (int i = 0; i < 128; ++i){
        unsigned u = row[i];
        acc += bflo(u) * bq[2*i] + bfhi(u) * bq[2*i + 1];
    }
    kb[m] = acc;
}

// ---------- LSTM cell, 8-wave variant: waves (gate g, K-half kh). K-half 0 = x@Wih, 1 = h@Whh ----------
// smemf layout: [8 waves][64 rows][17] floats (pad 17 breaks bank conflicts)
#define LG(w_, b_, j_) smemf[((w_)*64 + (b_))*17 + (j_)]
static __device__ __forceinline__ void lstm_part2(
    int tid, int jblk,
    const bf16_t* __restrict__ xrows, const bf16_t* __restrict__ emb,
    const int* __restrict__ y, int tok_col, int use_emb,
    const bf16_t* __restrict__ h_in, bf16_t* __restrict__ h_out,
    float* __restrict__ c_st, const bf16_t* __restrict__ Wcat,
    const float* __restrict__ bcat, bf16_t* __restrict__ xcat_out,
    float* smemf)
{
    const int lane = tid & 63, w = tid >> 6, ml = lane & 15, quad = lane >> 4;
    const int g = w & 3, kh = w >> 2;
    const int j0 = jblk * 16;
    const bf16_t* brow = Wcat + (size_t)(g*512 + j0 + ml) * 1024 + (size_t)kh * 512;
    const bf16_t* rA[4];
    #pragma unroll
    for (int mi = 0; mi < 4; ++mi){
        int b = mi*16 + ml;
        if (kh == 0){
            if (use_emb){
                int tok = (tok_col < 0) ? 0 : y[b * T_ + tok_col];   // SOS=0 at t=0
                rA[mi] = emb + (size_t)tok * 512;
            } else rA[mi] = xrows + (size_t)b * 512;
        } else {
            rA[mi] = h_in + (size_t)b * 512;
        }
    }
    floatx4 acc[4];
    #pragma unroll
    for (int mi = 0; mi < 4; ++mi) acc[mi] = (floatx4){0.f, 0.f, 0.f, 0.f};
    for (int ks = 0; ks < 512; ks += 32){
        int ko = ks + quad * 8;
        short8 bf = ld8(brow + ko);
        #pragma unroll
        for (int mi = 0; mi < 4; ++mi) acc[mi] = mfma16(ld8(rA[mi] + ko), bf, acc[mi]);
    }
    #pragma unroll
    for (int mi = 0; mi < 4; ++mi)
        #pragma unroll
        for (int r = 0; r < 4; ++r)
            LG(w, mi*16 + quad*4 + r, ml) = acc[mi][r];
    __syncthreads();
    // cell update: 512 threads x 2 cells (64 b x 16 j)
    const int jj = tid & 15, b0 = tid >> 4;  // b0 in [0,32)
    const int j = j0 + jj;
    const float bi = bcat[j], bff = bcat[512 + j], bg = bcat[1024 + j], bo = bcat[1536 + j];
    #pragma unroll
    for (int c = 0; c < 2; ++c){
        int b = b0 + 32 * c;
        float gi = LG(0, b, jj) + LG(4, b, jj) + bi;
        float gf = LG(1, b, jj) + LG(5, b, jj) + bff;
        float gg = LG(2, b, jj) + LG(6, b, jj) + bg;
        float go = LG(3, b, jj) + LG(7, b, jj) + bo;
        size_t idx = (size_t)b * 512 + j;
        float cn = sigm(gf) * c_st[idx] + sigm(gi) * tanh_(gg);
        float hn = sigm(go) * tanh_(cn);
        c_st[idx] = cn;
        bf16_t hb = f2bf(hn);
        h_out[idx] = hb;
        if (xcat_out) xcat_out[(size_t)b * 1024 + j] = hb;  // h2-half of [h2|ctx]
    }
}

// ---------- pipeA(t): LSTM2(t) [0,32) | ctx(t-1)+softmax [32,160) | logits(t-2) [160,168) ----------
__global__ __launch_bounds__(512) void pipeA_kernel(
    int t,
    const bf16_t* __restrict__ h1_x, const bf16_t* __restrict__ h2_in,
    bf16_t* __restrict__ h2_out, float* __restrict__ c2,
    const bf16_t* __restrict__ Wc2, const float* __restrict__ bcat2,
    bf16_t* __restrict__ xcat_t,
    const float* __restrict__ raw, const bf16_t* __restrict__ v16,
    bf16_t* __restrict__ xcat_tm1, float* __restrict__ out_attn,
    const bf16_t* __restrict__ hid_r, const bf16_t* __restrict__ emb16,
    const float* __restrict__ bcls, float* __restrict__ out_logits)
{
    __shared__ __align__(16) float smemf[8704];
    const int tid = threadIdx.x, bx = blockIdx.x;
    if (bx < 32){
        if (t >= T_) return;
        lstm_part2(tid, bx, h1_x, nullptr, nullptr, 0, 0,
                   h2_in, h2_out, c2, Wc2, bcat2, xcat_t, smemf);
    } else if (bx < 160){
        if (t < 1 || t > T_) return;
        // ctx(t-1): block = (b, eh); softmax of raw scores, then ctx e-half
        const int idx = bx - 32, b = idx >> 1, eh = idx & 1;
        float* attn_s = smemf;            // 512
        float* red    = smemf + 512;      // 16
        float* part   = smemf + 528;      // 16 sg x 32 cg x 9 (padded) = 4608
        const int s = tid;
        float sc = raw[(size_t)b * 512 + s];
        float mx = sc;
        #pragma unroll
        for (int o = 32; o > 0; o >>= 1) mx = fmaxf(mx, __shfl_xor(mx, o, 64));
        if ((tid & 63) == 0) red[tid >> 6] = mx;
        __syncthreads();
        float gmax = red[0];
        #pragma unroll
        for (int i = 1; i < 8; ++i) gmax = fmaxf(gmax, red[i]);
        float e = __expf(sc - gmax);
        float sm = e;
        #pragma unroll
        for (int o = 32; o > 0; o >>= 1) sm += __shfl_xor(sm, o, 64);
        if ((tid & 63) == 0) red[8 + (tid >> 6)] = sm;
        __syncthreads();
        float tot = red[8];
        #pragma unroll
        for (int i = 1; i < 8; ++i) tot += red[8 + i];
        float attn = e / tot;
        attn_s[s] = attn;
        if ((s >> 8) == eh)      // each block writes its s-half of out_attn
            out_attn[((size_t)b * T_ + (t - 1)) * S_ + s] = attn;
        __syncthreads();
        // ctx e-half: thread (cg=tid&31 -> 8 e-cols, sg=tid>>5 -> s stride 16)
        const int cg = tid & 31, sg = tid >> 5;
        const uint4* vb = (const uint4*)(v16 + ((size_t)b * 512) * 512 + eh*256 + cg*8);
        float cv[8] = {0.f,0.f,0.f,0.f,0.f,0.f,0.f,0.f};
        #pragma unroll 4
        for (int i = 0; i < 32; ++i){
            int sv = sg + 16 * i;
            uint4 vv = vb[(size_t)sv * 64];     // 64 uint4 per v-row
            float a = attn_s[sv];
            cv[0] += a * bflo(vv.x); cv[1] += a * bfhi(vv.x);
            cv[2] += a * bflo(vv.y); cv[3] += a * bfhi(vv.y);
            cv[4] += a * bflo(vv.z); cv[5] += a * bfhi(vv.z);
            cv[6] += a * bflo(vv.w); cv[7] += a * bfhi(vv.w);
        }
        #pragma unroll
        for (int e2 = 0; e2 < 8; ++e2) part[(sg*32 + cg)*9 + e2] = cv[e2];
        for (int off = 8; off > 0; off >>= 1){
            __syncthreads();
            if (sg < off){
                #pragma unroll
                for (int e2 = 0; e2 < 8; ++e2)
                    part[(sg*32 + cg)*9 + e2] += part[((sg + off)*32 + cg)*9 + e2];
            }
        }
        if (sg == 0){
            #pragma unroll
            for (int e2 = 0; e2 < 8; ++e2)
                xcat_tm1[(size_t)b * 1024 + 512 + eh*256 + cg*8 + e2] = f2bf(part[cg*9 + e2]);
        }
    } else {
        if (t < 2) return;
        // logits(t-2) = hid @ emb^T + bcls; 8 blocks x 8 waves x 16 n = N 1024 (pad of 1000)
        const int lane = tid & 63, w = tid >> 6, ml = lane & 15, quad = lane >> 4;
        const int nb = bx - 160;
        const int n = nb*128 + w*16 + ml;
        const bf16_t* brow = emb16 + (size_t)n * 512;
        const bf16_t* rA[4];
        #pragma unroll
        for (int mi = 0; mi < 4; ++mi) rA[mi] = hid_r + (size_t)(mi*16 + ml) * 512;
        floatx4 acc[4];
        #pragma unroll
        for (int mi = 0; mi < 4; ++mi) acc[mi] = (floatx4){0.f, 0.f, 0.f, 0.f};
        mfma_kloop(rA, brow, 512, quad, acc);
        if (n < V_){
            const float bias = bcls[n];
            #pragma unroll
            for (int mi = 0; mi < 4; ++mi)
                #pragma unroll
                for (int r = 0; r < 4; ++r){
                    int m = mi*16 + quad*4 + r;
                    out_logits[((size_t)m * T_ + (t - 2)) * V_ + n] = acc[mi][r] + bias;
                }
        }
    }
}

// ---------- pipeB(t): LSTM1(t+1) [0,32) | scores(t) [32,160) | hid(t-1) [160,164) ----------
__global__ __launch_bounds__(512) void pipeB_kernel(
    int t,
    const int* __restrict__ y, const bf16_t* __restrict__ emb16,
    const bf16_t* __restrict__ h1_in, bf16_t* __restrict__ h1_out, float* __restrict__ c1,
    const bf16_t* __restrict__ Wc1, const float* __restrict__ bcat1,
    const bf16_t* __restrict__ h2_t, const bf16_t* __restrict__ k216,
    const float* __restrict__ kb, float* __restrict__ raw,
    const bf16_t* __restrict__ xcat_tm1, const bf16_t* __restrict__ W116,
    const float* __restrict__ b1, bf16_t* __restrict__ hid_w)
{
    __shared__ __align__(16) float smemf[8704];
    const int tid = threadIdx.x, bx = blockIdx.x;
    if (bx < 32){
        if (t + 1 >= T_) return;
        lstm_part2(tid, bx, nullptr, emb16, y, t, 1,
                   h1_in, h1_out, c1, Wc1, bcat1, nullptr, smemf);
    } else if (bx < 160){
        if (t < 0 || t >= T_) return;
        // scores(t): block = (b, sh); 256 s-rows x H=512 dot with h2(t); 2 threads/row
        const int idx = bx - 32, b = idx >> 1, sh = idx & 1;
        float* h2s = smemf;   // 512 floats
        h2s[tid] = bf2f(h2_t[(size_t)b * 512 + tid]);
        __syncthreads();
        const int r = tid >> 1, hh = tid & 1;
        const uint4* krow = (const uint4*)(k216 + ((size_t)(b*512 + sh*256 + r)) * 512 + hh*256);
        float acc = 0.f;
        #pragma unroll 8
        for (int i = 0; i < 32; ++i){
            uint4 kv = krow[i];
            const float* hp = &h2s[hh*256 + i*8];
            acc += bflo(kv.x)*hp[0] + bfhi(kv.x)*hp[1]
                 + bflo(kv.y)*hp[2] + bfhi(kv.y)*hp[3]
                 + bflo(kv.z)*hp[4] + bfhi(kv.z)*hp[5]
                 + bflo(kv.w)*hp[6] + bfhi(kv.w)*hp[7];
        }
        acc += __shfl_xor(acc, 1, 64);
        if (hh == 0){
            int s = sh*256 + r;
            raw[(size_t)b*512 + s] = (acc + kb[(size_t)b*512 + s]) * 0.0625f;  // 1/sqrt(256)
        }
    } else {
        if (t < 1 || t > T_) return;
        // hid(t-1) = relu(xcat @ W1^T + b1); 4 blocks x 8 waves x 16 n = N 512, K=1024
        const int lane = tid & 63, w = tid >> 6, ml = lane & 15, quad = lane >> 4;
        const int nb = bx - 160;
        const int n = nb*128 + w*16 + ml;
        const bf16_t* brow = W116 + (size_t)n * 1024;
        const bf16_t* rA[4];
        #pragma unroll
        for (int mi = 0; mi < 4; ++mi) rA[mi] = xcat_tm1 + (size_t)(mi*16 + ml) * 1024;
        floatx4 acc[4];
        #pragma unroll
        for (int mi = 0; mi < 4; ++mi) acc[mi] = (floatx4){0.f, 0.f, 0.f, 0.f};
        mfma_kloop(rA, brow, 1024, quad, acc);
        const float bias = b1[n];
        #pragma unroll
        for (int mi = 0; mi < 4; ++mi)
            #pragma unroll
            for (int r = 0; r < 4; ++r){
                int m = mi*16 + quad*4 + r;
                float v_ = fmaxf(acc[mi][r] + bias, 0.f);
                hid_w[(size_t)m*512 + n] = f2bf(v_);
            }
    }
}

// ---------------------------------------------------------------------------
extern "C" void kernel_launch(void* const* d_in, const int* in_sizes, int n_in,
                              void* d_out, int out_size, void* d_ws, size_t ws_size,
                              hipStream_t stream)
{
    const float* enc  = (const float*)d_in[0];
    const int*   y    = (const int*)  d_in[1];
    const float* Wemb = (const float*)d_in[2];
    const float* Wih1 = (const float*)d_in[3];  const float* bih1 = (const float*)d_in[4];
    const float* Whh1 = (const float*)d_in[5];  const float* bhh1 = (const float*)d_in[6];
    const float* Wih2 = (const float*)d_in[7];  const float* bih2 = (const float*)d_in[8];
    const float* Whh2 = (const float*)d_in[9];  const float* bhh2 = (const float*)d_in[10];
    const float* Wq   = (const float*)d_in[11]; const float* bq   = (const float*)d_in[12];
    const float* Wk   = (const float*)d_in[13]; const float* bk   = (const float*)d_in[14];
    const float* Wv   = (const float*)d_in[15]; const float* bv   = (const float*)d_in[16];
    const float* W1   = (const float*)d_in[17]; const float* b1   = (const float*)d_in[18];
    const float* bcls = (const float*)d_in[19];

    float* outF = (float*)d_out;
    float* out_logits = outF;
    float* out_attn   = outF + (size_t)B_ * T_ * V_;

    // workspace carve (256B aligned). Peak use ~95 MB.
    size_t off = 0;
    char* wsb = (char*)d_ws;
    auto carve = [&](size_t bytes) -> void* {
        void* p = wsb + off;
        off += (bytes + 255) & ~(size_t)255;
        return p;
    };
    // enc16 is dead after gemm_kv_kernel; k216 aliases the same storage.
    bf16_t* enc16 = (bf16_t*)carve((size_t)B_*S_*E_*2);     // 33.5 MB (aliased by k216)
    bf16_t* k216  = enc16;
    bf16_t* kq16  = (bf16_t*)carve((size_t)B_*S_*KQ_*2);    // 16.8 MB
    bf16_t* v16   = (bf16_t*)carve((size_t)B_*S_*E_*2);     // 33.5 MB
    bf16_t* Wc1   = (bf16_t*)carve((size_t)2048*1024*2);
    bf16_t* Wc2   = (bf16_t*)carve((size_t)2048*1024*2);
    bf16_t* emb16 = (bf16_t*)carve((size_t)1024*512*2);     // padded to 1024 rows
    bf16_t* W116  = (bf16_t*)carve((size_t)512*1024*2);
    bf16_t* WqT16 = (bf16_t*)carve((size_t)512*256*2);
    bf16_t* Wkv16 = (bf16_t*)carve((size_t)768*512*2);
    float*  bcat1 = (float*) carve(2048*4);
    float*  bcat2 = (float*) carve(2048*4);
    float*  bkv   = (float*) carve(768*4);
    float*  kb    = (float*) carve((size_t)B_*S_*4);        // 128 KB
    float*  raw   = (float*) carve((size_t)B_*S_*4);        // raw scores scratch
    bf16_t* h1b   = (bf16_t*)carve((size_t)2*B_*H_*2);      // ping-pong
    bf16_t* h2b   = (bf16_t*)carve((size_t)2*B_*H_*2);
    float*  c1    = (float*) carve((size_t)B_*H_*4);
    float*  c2    = (float*) carve((size_t)B_*H_*4);
    bf16_t* xcat  = (bf16_t*)carve((size_t)2*B_*1024*2);    // [h2|ctx] ping-pong
    bf16_t* hid   = (bf16_t*)carve((size_t)2*B_*H_*2);      // ping-pong

    bf16_t* h1p[2]   = { h1b, h1b + (size_t)B_*H_ };
    bf16_t* h2p[2]   = { h2b, h2b + (size_t)B_*H_ };
    bf16_t* xcatp[2] = { xcat, xcat + (size_t)B_*1024 };
    bf16_t* hidp[2]  = { hid, hid + (size_t)B_*H_ };

    // zero recurrent state (ws is poisoned before every call)
    hipMemsetAsync(h1b, 0, (size_t)2*B_*H_*2, stream);
    hipMemsetAsync(h2b, 0, (size_t)2*B_*H_*2, stream);
    hipMemsetAsync(c1,  0, (size_t)B_*H_*4, stream);
    hipMemsetAsync(c2,  0, (size_t)B_*H_*4, stream);

    // setup: convert weights/enc, project k/v, fold Wq into k2, bq into kb
    convert_kernel<<<8192, 256, 0, stream>>>(enc, Wemb, Wih1, Whh1, Wih2, Whh2, Wq, Wk, Wv, W1,
                                             bih1, bhh1, bih2, bhh2, bk, bv,
                                             Wc1, Wc2, emb16, W116, WqT16, Wkv16, enc16,
                                             bcat1, bcat2, bkv);
    gemm_kv_kernel<<<dim3(512, 12), 256, 0, stream>>>(enc16, Wkv16, bkv, kq16, v16);
    gemm_k2_kernel<<<dim3(512, 8), 256, 0, stream>>>(kq16, WqT16, k216);
    kbias_kernel<<<128, 256, 0, stream>>>(kq16, bq, kb);

    // Software pipeline, 2 launches per step:
    //   pipeA(t): LSTM2(t) | ctx(t-1)+softmax | logits(t-2)
    //   pipeB(t): LSTM1(t+1) | scores(t) | hid(t-1)
    // h1(tau) lives in h1p[tau&1]; h2(tau) in h2p[tau&1]; xcat(tau) in xcatp[tau&1];
    // hid(tau) in hidp[tau&1]. All deps resolved by launch order (one stream).
    {
        // prime: LSTM1(0)  (reads h1(-1)=h1p[1], writes h1(0)=h1p[0])
        pipeB_kernel<<<164, 512, 0, stream>>>(-1, y, emb16, h1p[1], h1p[0], c1, Wc1, bcat1,
                                              h2p[1], k216, kb, raw,
                                              xcatp[0], W116, b1, hidp[0]);
    }
    for (int t = 0; t <= T_ + 1; ++t){
        const int i0 = (t + 2) & 1;   // == t&1 (safe for all t here)
        const int i1 = (t + 1) & 1;   // == (t-1)&1
        pipeA_kernel<<<168, 512, 0, stream>>>(t, h1p[i0], h2p[i1], h2p[i0], c2, Wc2, bcat2,
                                              xcatp[i0], raw, v16, xcatp[i1], out_attn,
                                              hidp[i0], emb16, bcls, out_logits);
        if (t <= T_)
            pipeB_kernel<<<164, 512, 0, stream>>>(t, y, emb16, h1p[i0], h1p[i1], c1, Wc1, bcat1,
                                                  h2p[i0], k216, kb, raw,
                                                  xcatp[i1], W116, b1, hidp[i1]);
    }
}

// Round 5
// 14185.397 us; speedup vs baseline: 1.4999x; 1.0920x over previous
//
#include <hip/hip_runtime.h>
#include <hip/hip_bf16.h>
#include <hip/hip_cooperative_groups.h>
#include <cstdint>
#include <cstddef>

namespace cg = cooperative_groups;

// Problem dims
#define B_   64
#define S_   512
#define T_   256
#define E_   512
#define H_   512
#define KQ_  256
#define V_   1000

typedef unsigned short bf16_t;
typedef __attribute__((ext_vector_type(8))) short short8;   // 8 bf16 (4 VGPRs) — MFMA A/B frag
typedef __attribute__((ext_vector_type(4))) float floatx4;  // MFMA C/D frag

// ---------- small helpers ----------
static __device__ __forceinline__ float bflo(unsigned u){ unsigned x = u << 16;        return __builtin_bit_cast(float, x); }
static __device__ __forceinline__ float bfhi(unsigned u){ unsigned x = u & 0xffff0000u; return __builtin_bit_cast(float, x); }
static __device__ __forceinline__ float bf2f(bf16_t h){ unsigned x = ((unsigned)h) << 16; return __builtin_bit_cast(float, x); }
static __device__ __forceinline__ bf16_t f2bf(float f){
    unsigned u = __builtin_bit_cast(unsigned, f);
    unsigned r = u + 0x7fffu + ((u >> 16) & 1u);   // RNE
    return (bf16_t)(r >> 16);
}
static __device__ __forceinline__ float sigm(float x){ return 1.f / (1.f + __expf(-x)); }
static __device__ __forceinline__ float tanh_(float x){
    float ax = fabsf(x); float t = __expf(-2.f * ax);
    float r = (1.f - t) / (1.f + t);
    return copysignf(r, x);
}
static __device__ __forceinline__ short8 ld8(const bf16_t* p){ return *(const short8*)p; }
static __device__ __forceinline__ floatx4 mfma16(short8 a, short8 b, floatx4 c){
    return __builtin_amdgcn_mfma_f32_16x16x32_bf16(a, b, c, 0, 0, 0);
}

// Shared MFMA K-loop: 4 M-tiles (M=64) x 1 N-tile (N=16) per wave.
// A frag: A[m=lane&15][k=quad*8+j]; B frag from W rows (B^T): B[n=lane&15][k].
// D frag: row(m)=quad*4+r, col(n)=lane&15  (m89-verified convention).
static __device__ __forceinline__ void mfma_kloop(const bf16_t* const rA[4], const bf16_t* rB,
                                                  int K, int quad, floatx4 acc[4]){
    for (int ks = 0; ks < K; ks += 32){
        int ko = ks + quad * 8;
        short8 bf = ld8(rB + ko);
        #pragma unroll
        for (int mi = 0; mi < 4; ++mi)
            acc[mi] = mfma16(ld8(rA[mi] + ko), bf, acc[mi]);
    }
}

// ---------- one-time conversion kernel ----------
// Segments (element index): Wcat1 | Wcat2 | emb(pad 1024 rows) | W1 | WqT | Wkv | enc | bcat1 | bcat2 | bkv
#define CV_E0 2097152UL
#define CV_E1 4194304UL
#define CV_E2 4718592UL
#define CV_E3 5242880UL
#define CV_E4 5373952UL
#define CV_E5 5767168UL
#define CV_E6 22544384UL
#define CV_E7 22546432UL
#define CV_E8 22548480UL
#define CV_E9 22549248UL

__global__ __launch_bounds__(256) void convert_kernel(
    const float* __restrict__ enc,  const float* __restrict__ Wemb,
    const float* __restrict__ Wih1, const float* __restrict__ Whh1,
    const float* __restrict__ Wih2, const float* __restrict__ Whh2,
    const float* __restrict__ Wq,   const float* __restrict__ Wk,
    const float* __restrict__ Wv,   const float* __restrict__ W1,
    const float* __restrict__ bih1, const float* __restrict__ bhh1,
    const float* __restrict__ bih2, const float* __restrict__ bhh2,
    const float* __restrict__ bk,   const float* __restrict__ bv,
    bf16_t* __restrict__ Wc1,  bf16_t* __restrict__ Wc2, bf16_t* __restrict__ emb16,
    bf16_t* __restrict__ W116, bf16_t* __restrict__ WqT16, bf16_t* __restrict__ Wkv16,
    bf16_t* __restrict__ enc16, float* __restrict__ bcat1, float* __restrict__ bcat2,
    float* __restrict__ bkvO)
{
    for (size_t i = (size_t)blockIdx.x * 256 + threadIdx.x; i < CV_E9; i += (size_t)gridDim.x * 256){
        if (i < CV_E0){ size_t r = i >> 10, k = i & 1023;
            float v_ = (k < 512) ? Wih1[r*512 + k] : Whh1[r*512 + (k - 512)];
            Wc1[i] = f2bf(v_);
        } else if (i < CV_E1){ size_t l = i - CV_E0, r = l >> 10, k = l & 1023;
            float v_ = (k < 512) ? Wih2[r*512 + k] : Whh2[r*512 + (k - 512)];
            Wc2[l] = f2bf(v_);
        } else if (i < CV_E2){ size_t l = i - CV_E1, r = l >> 9, k = l & 511;
            emb16[l] = f2bf(r < 1000 ? Wemb[r*512 + k] : 0.f);
        } else if (i < CV_E3){ size_t l = i - CV_E2;
            W116[l] = f2bf(W1[l]);
        } else if (i < CV_E4){ size_t l = i - CV_E3, h = l >> 8, nn = l & 255;
            WqT16[l] = f2bf(Wq[nn*512 + h]);     // WqT[h][d] = Wq[d][h]
        } else if (i < CV_E5){ size_t l = i - CV_E4, r = l >> 9, k = l & 511;
            float v_ = (r < 256) ? Wk[r*512 + k] : Wv[(r - 256)*512 + k];
            Wkv16[l] = f2bf(v_);
        } else if (i < CV_E6){ size_t l = i - CV_E5;
            enc16[l] = f2bf(enc[l]);
        } else if (i < CV_E7){ size_t l = i - CV_E6; bcat1[l] = bih1[l] + bhh1[l]; }
        else if (i < CV_E8){ size_t l = i - CV_E7; bcat2[l] = bih2[l] + bhh2[l]; }
        else { size_t l = i - CV_E8; bkvO[l] = (l < 256) ? bk[l] : bv[l - 256]; }
    }
}

// ---------- k/v projection: [k|v](m,n) = enc(m,:) . Wkv(n,:) + bkv(n);  M=32768, N=768, K=512 ----------
__global__ __launch_bounds__(256) void gemm_kv_kernel(
    const bf16_t* __restrict__ enc16, const bf16_t* __restrict__ Wkv16,
    const float* __restrict__ bkv, bf16_t* __restrict__ kq16, bf16_t* __restrict__ v16)
{
    const int tid = threadIdx.x, lane = tid & 63, wv = tid >> 6, ml = lane & 15, quad = lane >> 4;
    const int mb = blockIdx.x, nb = blockIdx.y;
    const int n = nb*64 + wv*16 + ml;
    const bf16_t* brow = Wkv16 + (size_t)n * 512;
    const bf16_t* rA[4];
    #pragma unroll
    for (int mi = 0; mi < 4; ++mi) rA[mi] = enc16 + (size_t)(mb*64 + mi*16 + ml) * 512;
    floatx4 acc[4];
    #pragma unroll
    for (int mi = 0; mi < 4; ++mi) acc[mi] = (floatx4){0.f, 0.f, 0.f, 0.f};
    mfma_kloop(rA, brow, 512, quad, acc);
    const float bias = bkv[n];
    #pragma unroll
    for (int mi = 0; mi < 4; ++mi)
        #pragma unroll
        for (int r = 0; r < 4; ++r){
            int m = mb*64 + mi*16 + quad*4 + r;
            float val = acc[mi][r] + bias;
            if (n < 256) kq16[(size_t)m*256 + n] = f2bf(val);
            else         v16 [(size_t)m*512 + (n - 256)] = f2bf(val);
        }
}

// ---------- k2 = k @ Wq: M=32768, N=512, K=256 ----------
__global__ __launch_bounds__(256) void gemm_k2_kernel(
    const bf16_t* __restrict__ kq16, const bf16_t* __restrict__ WqT16, bf16_t* __restrict__ k216)
{
    const int tid = threadIdx.x, lane = tid & 63, wv = tid >> 6, ml = lane & 15, quad = lane >> 4;
    const int mb = blockIdx.x, nb = blockIdx.y;
    const int n = nb*64 + wv*16 + ml;
    const bf16_t* brow = WqT16 + (size_t)n * 256;
    const bf16_t* rA[4];
    #pragma unroll
    for (int mi = 0; mi < 4; ++mi) rA[mi] = kq16 + (size_t)(mb*64 + mi*16 + ml) * 256;
    floatx4 acc[4];
    #pragma unroll
    for (int mi = 0; mi < 4; ++mi) acc[mi] = (floatx4){0.f, 0.f, 0.f, 0.f};
    mfma_kloop(rA, brow, 256, quad, acc);
    #pragma unroll
    for (int mi = 0; mi < 4; ++mi)
        #pragma unroll
        for (int r = 0; r < 4; ++r){
            int m = mb*64 + mi*16 + quad*4 + r;
            k216[(size_t)m*512 + n] = f2bf(acc[mi][r]);
        }
}

// ---------- kb[m] = k[m,:] . bq ----------
__global__ __launch_bounds__(256) void kbias_kernel(
    const bf16_t* __restrict__ kq16, const float* __restrict__ bq, float* __restrict__ kb)
{
    int m = blockIdx.x * 256 + threadIdx.x;  // 32768 total
    const unsigned* row = (const unsigned*)(kq16 + (size_t)m * 256);
    float acc = 0.f;
    #pragma unroll 8
    for (int i = 0; i < 128; ++i){
        unsigned u = row[i];
        acc += bflo(u) * bq[2*i] + bfhi(u) * bq[2*i + 1];
    }
    kb[m] = acc;
}

// ---------- LSTM cell, 8-wave variant: waves (gate g, K-half kh). K-half 0 = x@Wih, 1 = h@Whh ----------
// smemf layout: [8 waves][64 rows][17] floats (pad 17 breaks bank conflicts)
#define LG(w_, b_, j_) smemf[((w_)*64 + (b_))*17 + (j_)]
static __device__ __forceinline__ void lstm_part2(
    int tid, int jblk,
    const bf16_t* __restrict__ xrows, const bf16_t* __restrict__ emb,
    const int* __restrict__ y, int tok_col, int use_emb,
    const bf16_t* __restrict__ h_in, bf16_t* __restrict__ h_out,
    float* __restrict__ c_st, const bf16_t* __restrict__ Wcat,
    const float* __restrict__ bcat, bf16_t* __restrict__ xcat_out,
    float* smemf)
{
    const int lane = tid & 63, w = tid >> 6, ml = lane & 15, quad = lane >> 4;
    const int g = w & 3, kh = w >> 2;
    const int j0 = jblk * 16;
    const bf16_t* brow = Wcat + (size_t)(g*512 + j0 + ml) * 1024 + (size_t)kh * 512;
    const bf16_t* rA[4];
    #pragma unroll
    for (int mi = 0; mi < 4; ++mi){
        int b = mi*16 + ml;
        if (kh == 0){
            if (use_emb){
                int tok = (tok_col < 0) ? 0 : y[b * T_ + tok_col];   // SOS=0
                rA[mi] = emb + (size_t)tok * 512;
            } else rA[mi] = xrows + (size_t)b * 512;
        } else {
            rA[mi] = h_in + (size_t)b * 512;
        }
    }
    floatx4 acc[4];
    #pragma unroll
    for (int mi = 0; mi < 4; ++mi) acc[mi] = (floatx4){0.f, 0.f, 0.f, 0.f};
    for (int ks = 0; ks < 512; ks += 32){
        int ko = ks + quad * 8;
        short8 bf = ld8(brow + ko);
        #pragma unroll
        for (int mi = 0; mi < 4; ++mi) acc[mi] = mfma16(ld8(rA[mi] + ko), bf, acc[mi]);
    }
    #pragma unroll
    for (int mi = 0; mi < 4; ++mi)
        #pragma unroll
        for (int r = 0; r < 4; ++r)
            LG(w, mi*16 + quad*4 + r, ml) = acc[mi][r];
    __syncthreads();
    // cell update: 512 threads x 2 cells (64 b x 16 j)
    const int jj = tid & 15, b0 = tid >> 4;  // b0 in [0,32)
    const int j = j0 + jj;
    const float bi = bcat[j], bff = bcat[512 + j], bg = bcat[1024 + j], bo = bcat[1536 + j];
    #pragma unroll
    for (int c = 0; c < 2; ++c){
        int b = b0 + 32 * c;
        float gi = LG(0, b, jj) + LG(4, b, jj) + bi;
        float gf = LG(1, b, jj) + LG(5, b, jj) + bff;
        float gg = LG(2, b, jj) + LG(6, b, jj) + bg;
        float go = LG(3, b, jj) + LG(7, b, jj) + bo;
        size_t idx = (size_t)b * 512 + j;
        float cn = sigm(gf) * c_st[idx] + sigm(gi) * tanh_(gg);
        float hn = sigm(go) * tanh_(cn);
        c_st[idx] = cn;
        bf16_t hb = f2bf(hn);
        h_out[idx] = hb;
        if (xcat_out) xcat_out[(size_t)b * 1024 + j] = hb;  // h2-half of [h2|ctx]
    }
}

// ---------- persistent cooperative kernel: whole scan, 1 barrier per pipeline period ----------
// Period p: LSTM1(p) | LSTM2->h2(p-1) | scores(p-2) | softmax+ctx(p-3) | hid(p-4) | logits(p-5)
// Buffers: h1/h2/raw/hid ping-pong by t&1; xcat depth-4 by t&3 (h2-half @t+1, ctx-half @t+3, read @t+4).
// Grid = 204 blocks <= 256 CUs: co-residency guaranteed at 1 block/CU
// (LDS 34.8 KB < 64 KB/WG, any VGPR count) -> cooperative capacity check passes.
struct PersistParams {
    const int* y;
    const bf16_t *emb16, *Wc1, *Wc2, *W116, *k216, *v16;
    const float *bcat1, *bcat2, *b1, *bcls, *kb;
    bf16_t *h1, *h2, *xcat, *hidb;
    float *c1, *c2, *raw;
    float *out_logits, *out_attn;
};

#define NPER (T_ + 5)   // 261 periods

__global__ __launch_bounds__(512, 2) void persist_kernel(PersistParams P)
{
    cg::grid_group gg = cg::this_grid();
    __shared__ __align__(16) float smemf[8704];
    const int bx = blockIdx.x, tid = threadIdx.x;
    const size_t BH = (size_t)B_ * H_, BS = (size_t)B_ * S_, B1K = (size_t)B_ * 1024;

    for (int p = 0; p < NPER; ++p){
        if (bx < 32){
            // ---- LSTM1(t=p): h1[p&1] <- f(emb(y,p-1), h1[(p-1)&1]) ----
            int t = p;
            if (t < T_){
                lstm_part2(tid, bx, nullptr, P.emb16, P.y, t - 1, 1,
                           P.h1 + ((t - 1) & 1) * BH, P.h1 + (t & 1) * BH,
                           P.c1, P.Wc1, P.bcat1, nullptr, smemf);
            }
        } else if (bx < 64){
            // ---- LSTM2(t=p-1): h2[t&1] <- f(h1[t&1], h2[(t-1)&1]); writes h2-half of xcat[t&3] ----
            int t = p - 1;
            if (t >= 0 && t < T_){
                lstm_part2(tid, bx - 32, P.h1 + (t & 1) * BH, nullptr, nullptr, 0, 0,
                           P.h2 + ((t - 1) & 1) * BH, P.h2 + (t & 1) * BH,
                           P.c2, P.Wc2, P.bcat2, P.xcat + (t & 3) * B1K, smemf);
            }
        } else if (bx < 128){
            // ---- scores(t=p-2): raw[t&1][b][s] <- (h2(t).k2[b][s] + kb)/16; 1 block/batch, thread=s ----
            int t = p - 2;
            if (t >= 0 && t < T_){
                const int b = bx - 64;
                const bf16_t* h2_t = P.h2 + (t & 1) * BH;
                float* rawW = P.raw + (t & 1) * BS;
                float* h2s = smemf;   // 512 floats
                h2s[tid] = bf2f(h2_t[(size_t)b * 512 + tid]);
                __syncthreads();
                const int s = tid;
                const uint4* krow = (const uint4*)(P.k216 + ((size_t)(b*512 + s)) * 512);
                float acc = 0.f;
                #pragma unroll 8
                for (int i = 0; i < 64; ++i){
                    uint4 kv = krow[i];
                    const float* hp = &h2s[i*8];
                    acc += bflo(kv.x)*hp[0] + bfhi(kv.x)*hp[1]
                         + bflo(kv.y)*hp[2] + bfhi(kv.y)*hp[3]
                         + bflo(kv.z)*hp[4] + bfhi(kv.z)*hp[5]
                         + bflo(kv.w)*hp[6] + bfhi(kv.w)*hp[7];
                }
                rawW[(size_t)b*512 + s] = (acc + P.kb[(size_t)b*512 + s]) * 0.0625f;
                __syncthreads();   // protect smemf before next period
            }
        } else if (bx < 192){
            // ---- softmax+ctx(t=p-3): reads raw[t&1]; writes ctx-half of xcat[t&3], out_attn(t);
            //      1 block/batch: 64 e-groups (8 e each) x 8 s-groups ----
            int t = p - 3;
            if (t >= 0 && t < T_){
                const int b = bx - 128;
                const float* rawR = P.raw + (t & 1) * BS;
                bf16_t* xc = P.xcat + (t & 3) * B1K;
                float* attn_s = smemf;            // 512
                float* red    = smemf + 512;      // 16
                float* part   = smemf + 528;      // 8 sg x 64 cg x 9 = 4608
                const int s = tid;
                float sc = rawR[(size_t)b * 512 + s];
                float mx = sc;
                #pragma unroll
                for (int o = 32; o > 0; o >>= 1) mx = fmaxf(mx, __shfl_xor(mx, o, 64));
                if ((tid & 63) == 0) red[tid >> 6] = mx;
                __syncthreads();
                float gmax = red[0];
                #pragma unroll
                for (int i = 1; i < 8; ++i) gmax = fmaxf(gmax, red[i]);
                float e = __expf(sc - gmax);
                float sm = e;
                #pragma unroll
                for (int o = 32; o > 0; o >>= 1) sm += __shfl_xor(sm, o, 64);
                if ((tid & 63) == 0) red[8 + (tid >> 6)] = sm;
                __syncthreads();
                float tot = red[8];
                #pragma unroll
                for (int i = 1; i < 8; ++i) tot += red[8 + i];
                float attn = e / tot;
                attn_s[s] = attn;
                P.out_attn[((size_t)b * T_ + t) * S_ + s] = attn;
                __syncthreads();
                const int cg_ = tid & 63, sg = tid >> 6;    // 64 e-groups x 8 s-groups
                const uint4* vb = (const uint4*)(P.v16 + (size_t)b * 512 * 512) + cg_;
                float cv[8] = {0.f,0.f,0.f,0.f,0.f,0.f,0.f,0.f};
                #pragma unroll 4
                for (int i = 0; i < 64; ++i){
                    int sv = sg + 8 * i;
                    uint4 vv = vb[(size_t)sv * 64];     // 64 uint4 per v-row
                    float a = attn_s[sv];
                    cv[0] += a * bflo(vv.x); cv[1] += a * bfhi(vv.x);
                    cv[2] += a * bflo(vv.y); cv[3] += a * bfhi(vv.y);
                    cv[4] += a * bflo(vv.z); cv[5] += a * bfhi(vv.z);
                    cv[6] += a * bflo(vv.w); cv[7] += a * bfhi(vv.w);
                }
                #pragma unroll
                for (int e2 = 0; e2 < 8; ++e2) part[(sg*64 + cg_)*9 + e2] = cv[e2];
                for (int off = 4; off > 0; off >>= 1){
                    __syncthreads();
                    if (sg < off){
                        #pragma unroll
                        for (int e2 = 0; e2 < 8; ++e2)
                            part[(sg*64 + cg_)*9 + e2] += part[((sg + off)*64 + cg_)*9 + e2];
                    }
                }
                if (sg == 0){
                    #pragma unroll
                    for (int e2 = 0; e2 < 8; ++e2)
                        xc[(size_t)b * 1024 + 512 + cg_*8 + e2] = f2bf(part[cg_*9 + e2]);
                }
                __syncthreads();
            }
        } else if (bx < 196){
            // ---- hid(t=p-4) = relu(xcat[t&3] @ W1^T + b1) -> hidb[t&1]; N=512, K=1024 ----
            int t = p - 4;
            if (t >= 0 && t < T_){
                const int lane = tid & 63, w = tid >> 6, ml = lane & 15, quad = lane >> 4;
                const int nb = bx - 192;
                const int n = nb*128 + w*16 + ml;
                const bf16_t* xr = P.xcat + (t & 3) * B1K;
                bf16_t* hw = P.hidb + (t & 1) * BH;
                const bf16_t* brow = P.W116 + (size_t)n * 1024;
                const bf16_t* rA[4];
                #pragma unroll
                for (int mi = 0; mi < 4; ++mi) rA[mi] = xr + (size_t)(mi*16 + ml) * 1024;
                floatx4 acc[4];
                #pragma unroll
                for (int mi = 0; mi < 4; ++mi) acc[mi] = (floatx4){0.f, 0.f, 0.f, 0.f};
                mfma_kloop(rA, brow, 1024, quad, acc);
                const float bias = P.b1[n];
                #pragma unroll
                for (int mi = 0; mi < 4; ++mi)
                    #pragma unroll
                    for (int r = 0; r < 4; ++r){
                        int m = mi*16 + quad*4 + r;
                        float v_ = fmaxf(acc[mi][r] + bias, 0.f);
                        hw[(size_t)m*512 + n] = f2bf(v_);
                    }
            }
        } else {
            // ---- logits(t=p-5) = hidb[t&1] @ emb^T + bcls; N=1024 (pad of 1000), K=512; 8 blocks ----
            int t = p - 5;
            if (t >= 0 && t < T_){
                const int lane = tid & 63, w = tid >> 6, ml = lane & 15, quad = lane >> 4;
                const int nb = bx - 196;
                const int n = nb*128 + w*16 + ml;
                const bf16_t* hr = P.hidb + (t & 1) * BH;
                const bf16_t* brow = P.emb16 + (size_t)n * 512;
                const bf16_t* rA[4];
                #pragma unroll
                for (int mi = 0; mi < 4; ++mi) rA[mi] = hr + (size_t)(mi*16 + ml) * 512;
                floatx4 acc[4];
                #pragma unroll
                for (int mi = 0; mi < 4; ++mi) acc[mi] = (floatx4){0.f, 0.f, 0.f, 0.f};
                mfma_kloop(rA, brow, 512, quad, acc);
                if (n < V_){
                    const float bias = P.bcls[n];
                    #pragma unroll
                    for (int mi = 0; mi < 4; ++mi)
                        #pragma unroll
                        for (int r = 0; r < 4; ++r){
                            int m = mi*16 + quad*4 + r;
                            P.out_logits[((size_t)m * T_ + t) * V_ + n] = acc[mi][r] + bias;
                        }
                }
            }
        }
        gg.sync();
    }
}

// ---------------------------------------------------------------------------
extern "C" void kernel_launch(void* const* d_in, const int* in_sizes, int n_in,
                              void* d_out, int out_size, void* d_ws, size_t ws_size,
                              hipStream_t stream)
{
    const float* enc  = (const float*)d_in[0];
    const int*   y    = (const int*)  d_in[1];
    const float* Wemb = (const float*)d_in[2];
    const float* Wih1 = (const float*)d_in[3];  const float* bih1 = (const float*)d_in[4];
    const float* Whh1 = (const float*)d_in[5];  const float* bhh1 = (const float*)d_in[6];
    const float* Wih2 = (const float*)d_in[7];  const float* bih2 = (const float*)d_in[8];
    const float* Whh2 = (const float*)d_in[9];  const float* bhh2 = (const float*)d_in[10];
    const float* Wq   = (const float*)d_in[11]; const float* bq   = (const float*)d_in[12];
    const float* Wk   = (const float*)d_in[13]; const float* bk   = (const float*)d_in[14];
    const float* Wv   = (const float*)d_in[15]; const float* bv   = (const float*)d_in[16];
    const float* W1   = (const float*)d_in[17]; const float* b1   = (const float*)d_in[18];
    const float* bcls = (const float*)d_in[19];

    float* outF = (float*)d_out;
    float* out_logits = outF;
    float* out_attn   = outF + (size_t)B_ * T_ * V_;

    // workspace carve (256B aligned). Peak use ~95 MB.
    size_t off = 0;
    char* wsb = (char*)d_ws;
    auto carve = [&](size_t bytes) -> void* {
        void* p = wsb + off;
        off += (bytes + 255) & ~(size_t)255;
        return p;
    };
    bf16_t* enc16 = (bf16_t*)carve((size_t)B_*S_*E_*2);     // 33.5 MB (aliased by k216)
    bf16_t* k216  = enc16;
    bf16_t* kq16  = (bf16_t*)carve((size_t)B_*S_*KQ_*2);    // 16.8 MB
    bf16_t* v16   = (bf16_t*)carve((size_t)B_*S_*E_*2);     // 33.5 MB
    bf16_t* Wc1   = (bf16_t*)carve((size_t)2048*1024*2);
    bf16_t* Wc2   = (bf16_t*)carve((size_t)2048*1024*2);
    bf16_t* emb16 = (bf16_t*)carve((size_t)1024*512*2);     // padded to 1024 rows
    bf16_t* W116  = (bf16_t*)carve((size_t)512*1024*2);
    bf16_t* WqT16 = (bf16_t*)carve((size_t)512*256*2);
    bf16_t* Wkv16 = (bf16_t*)carve((size_t)768*512*2);
    float*  bcat1 = (float*) carve(2048*4);
    float*  bcat2 = (float*) carve(2048*4);
    float*  bkv   = (float*) carve(768*4);
    float*  kb    = (float*) carve((size_t)B_*S_*4);        // 128 KB
    float*  raw   = (float*) carve((size_t)2*B_*S_*4);      // raw scores ping-pong
    bf16_t* h1b   = (bf16_t*)carve((size_t)2*B_*H_*2);      // ping-pong
    bf16_t* h2b   = (bf16_t*)carve((size_t)2*B_*H_*2);
    float*  c1    = (float*) carve((size_t)B_*H_*4);
    float*  c2    = (float*) carve((size_t)B_*H_*4);
    bf16_t* xcat  = (bf16_t*)carve((size_t)4*B_*1024*2);    // depth-4
    bf16_t* hid   = (bf16_t*)carve((size_t)2*B_*H_*2);      // ping-pong

    // zero recurrent state (ws is poisoned before every call)
    hipMemsetAsync(h1b, 0, (size_t)2*B_*H_*2, stream);
    hipMemsetAsync(h2b, 0, (size_t)2*B_*H_*2, stream);
    hipMemsetAsync(c1,  0, (size_t)B_*H_*4, stream);
    hipMemsetAsync(c2,  0, (size_t)B_*H_*4, stream);

    // setup: convert weights/enc, project k/v, fold Wq into k2, bq into kb
    convert_kernel<<<8192, 256, 0, stream>>>(enc, Wemb, Wih1, Whh1, Wih2, Whh2, Wq, Wk, Wv, W1,
                                             bih1, bhh1, bih2, bhh2, bk, bv,
                                             Wc1, Wc2, emb16, W116, WqT16, Wkv16, enc16,
                                             bcat1, bcat2, bkv);
    gemm_kv_kernel<<<dim3(512, 12), 256, 0, stream>>>(enc16, Wkv16, bkv, kq16, v16);
    gemm_k2_kernel<<<dim3(512, 8), 256, 0, stream>>>(kq16, WqT16, k216);
    kbias_kernel<<<128, 256, 0, stream>>>(kq16, bq, kb);

    // whole scan in one persistent cooperative kernel (261 grid barriers)
    PersistParams prm;
    prm.y = y; prm.emb16 = emb16; prm.Wc1 = Wc1; prm.Wc2 = Wc2; prm.W116 = W116;
    prm.k216 = k216; prm.v16 = v16;
    prm.bcat1 = bcat1; prm.bcat2 = bcat2; prm.b1 = b1; prm.bcls = bcls; prm.kb = kb;
    prm.h1 = h1b; prm.h2 = h2b; prm.xcat = xcat; prm.hidb = hid;
    prm.c1 = c1; prm.c2 = c2; prm.raw = raw;
    prm.out_logits = out_logits; prm.out_attn = out_attn;

    void* kargs[] = { (void*)&prm };
    hipLaunchCooperativeKernel((const void*)persist_kernel, dim3(204), dim3(512),
                               kargs, 0, stream);
}